// Round 1
// baseline (52.264 us; speedup 1.0000x reference)
//
#include <hip/hip_runtime.h>

#define NP 96          // Np = Mp = 96 (95 nodes + 1 eps)
#define NREAL 95
#define NLAB 8
#define SINK_ITERS 10

// ---------------------------------------------------------------------------
// K1: single block. Build NCx (9x9 node cost table), init M = exp(-0.5*cvec),
// run 10 Sinkhorn iterations in LDS, write S to workspace, write linear term
// (cvec . v) into out[0].
// ---------------------------------------------------------------------------
__global__ __launch_bounds__(1024) void ged_sinkhorn(
    const int* __restrict__ l1, const int* __restrict__ l2,
    const float* __restrict__ nodeW,
    float* __restrict__ S_out, float* __restrict__ out)
{
    __shared__ float S[NP][NP];      // LD=96: row pass lane-contiguous, col pass thread-per-col both conflict-free
    __shared__ float NC[9][9];
    __shared__ float ENC[9][9];      // exp(-0.5*NC)
    __shared__ int   l1e[NP], l2e[NP];
    __shared__ float colp[4][NP];    // column partial sums (4 row-segments)
    __shared__ float colinv[NP];
    __shared__ float wpart[16];

    const int t = threadIdx.x;
    const int lane = t & 63;
    const int wave = t >> 6;

    // Build NCx and exp table (node_costs diag = 0; row/col 8 = nodeInsDel; [8][8]=0)
    if (t < 81) {
        int r = t / 9, c = t % 9;
        float v;
        if (r == c) v = 0.f;
        else if (r == NLAB || c == NLAB) v = fmaxf(nodeW[28], 0.f);
        else {
            int rr = min(r, c), cc = max(r, c);
            int p = rr * (15 - rr) / 2 + (cc - rr - 1);   // triu_indices(8,1) linear index
            v = fmaxf(nodeW[p], 0.f);
        }
        NC[r][c] = v;
        ENC[r][c] = expf(-0.5f * v);
    }
    if (t < NP) {
        l1e[t] = (t < NREAL) ? l1[t] : NLAB;
        l2e[t] = (t < NREAL) ? l2[t] : NLAB;
    }
    __syncthreads();

    // Init M[i][k] = exp(-0.5 * NCx[l1e[i], l2e[k]])
    for (int e = t; e < NP * NP; e += 1024) {
        int i = e / NP, k = e % NP;
        S[i][k] = ENC[l1e[i]][l2e[k]];
    }
    __syncthreads();

    for (int iter = 0; iter < SINK_ITERS; ++iter) {
        // ---- row normalize: wave w handles rows w, w+16, ...
        for (int r = wave; r < NP; r += 16) {
            float s1 = S[r][lane];
            float s2 = (lane < 32) ? S[r][64 + lane] : 0.f;
            float sum = s1 + s2;
            #pragma unroll
            for (int off = 32; off >= 1; off >>= 1) sum += __shfl_xor(sum, off, 64);
            float inv = 1.f / sum;
            S[r][lane] = s1 * inv;
            if (lane < 32) S[r][64 + lane] = s2 * inv;
        }
        __syncthreads();

        // ---- column sums (4 segments of 24 rows each, then combine)
        if (t < 4 * NP) {
            int c = t % NP, seg = t / NP;
            float acc = 0.f;
            int r0 = seg * 24;
            for (int r = r0; r < r0 + 24; ++r) acc += S[r][c];
            colp[seg][c] = acc;
        }
        __syncthreads();
        if (t < NP)
            colinv[t] = 1.f / (colp[0][t] + colp[1][t] + colp[2][t] + colp[3][t]);
        __syncthreads();
        for (int e = t; e < NP * NP; e += 1024) {
            int i = e / NP, k = e % NP;
            S[i][k] *= colinv[k];
        }
        __syncthreads();
    }

    // Write S to workspace + linear term cvec.v
    float lacc = 0.f;
    for (int e = t; e < NP * NP; e += 1024) {
        int i = e / NP, k = e % NP;
        float s = S[i][k];
        S_out[e] = s;
        lacc += NC[l1e[i]][l2e[k]] * s;
    }
    #pragma unroll
    for (int off = 32; off >= 1; off >>= 1) lacc += __shfl_xor(lacc, off, 64);
    if (lane == 0) wpart[wave] = lacc;
    __syncthreads();
    if (t == 0) {
        float tot = 0.f;
        #pragma unroll
        for (int w = 0; w < 16; ++w) tot += wpart[w];
        out[0] = tot;     // K2 atomically adds the quadratic term on top
    }
}

// ---------------------------------------------------------------------------
// K2: one block per k-column (96 blocks). Computes
//   partial_k = sum_j S[j,k] * sum_i V[i][a1c[i,j]],
//   V[i][e]   = sum_l EC[e, a2c[k,l]] * S[i,l]
// and atomicAdds 0.5*partial_k into out[0].
// ---------------------------------------------------------------------------
__global__ __launch_bounds__(256) void ged_quad(
    const int* __restrict__ A1, const int* __restrict__ A2,
    const float* __restrict__ edgeW, const float* __restrict__ S_in,
    float* __restrict__ out)
{
    __shared__ float S[NP][NP + 1];   // pad: phase-A reads stride-97 across i -> conflict-free
    __shared__ float EC[4][4];
    __shared__ float ecl[NP][4];      // ecl[l][e] = EC[e][a2c[k][l]]
    __shared__ float Vp[2][4][NP];    // half-range partials
    __shared__ float V[NP][4];        // V[i][e]  (layout i-major: 4-bank spread on gather)
    __shared__ float red[4];

    const int k = blockIdx.x;
    const int t = threadIdx.x;

    // EC 4x4: [0][0]=0, row/col0 = edgeInsDel, inner = edge_costs (zero diag)
    if (t < 16) {
        int r = t / 4, c = t % 4;
        float v;
        if (r == c) v = 0.f;
        else if (r == 0 || c == 0) v = fmaxf(edgeW[3], 0.f);
        else {
            int rr = min(r, c) - 1, cc = max(r, c) - 1;
            int p = rr * (5 - rr) / 2 + (cc - rr - 1);   // triu_indices(3,1)
            v = fmaxf(edgeW[p], 0.f);
        }
        EC[r][c] = v;
    }
    // Load S
    for (int e = t; e < NP * NP; e += 256)
        S[e / NP][e % NP] = S_in[e];
    __syncthreads();

    // ecl[l][e]
    if (t < NP) {
        int l = t;
        int c = (k < NREAL && l < NREAL) ? A2[k * NREAL + l] : 0;
        #pragma unroll
        for (int e = 0; e < 4; ++e) ecl[l][e] = EC[e][c];
    }
    __syncthreads();

    // Phase A: V[i][e] = sum_l ecl[l][e]*S[i][l]; 2 threads per row i (half l-range each)
    if (t < 192) {
        int i = t >> 1, h = t & 1;
        float v0 = 0.f, v1 = 0.f, v2 = 0.f, v3 = 0.f;
        int l0 = h * 48;
        for (int l = l0; l < l0 + 48; ++l) {
            float s = S[i][l];
            v0 += s * ecl[l][0];
            v1 += s * ecl[l][1];
            v2 += s * ecl[l][2];
            v3 += s * ecl[l][3];
        }
        Vp[h][0][i] = v0; Vp[h][1][i] = v1; Vp[h][2][i] = v2; Vp[h][3][i] = v3;
    }
    __syncthreads();
    if (t < NP) {
        #pragma unroll
        for (int e = 0; e < 4; ++e) V[t][e] = Vp[0][e][t] + Vp[1][e][t];
    }
    __syncthreads();

    // Phase B: thread j: w = sum_i V[i][a1c[i,j]]; partial = S[j][k]*w
    float part = 0.f;
    if (t < NP) {
        int j = t;
        float w = 0.f;
        if (j < NREAL) {
            for (int i = 0; i < NREAL; ++i) {
                int c = A1[i * NREAL + j];   // coalesced across j
                w += V[i][c];
            }
            w += V[NREAL][0];                // padded row i=95 -> code 0
        } else {
            for (int i = 0; i < NP; ++i) w += V[i][0];
        }
        part = S[j][k] * w;
    }
    // Block reduce
    const int lane = t & 63, wave = t >> 6;
    #pragma unroll
    for (int off = 32; off >= 1; off >>= 1) part += __shfl_xor(part, off, 64);
    if (lane == 0) red[wave] = part;
    __syncthreads();
    if (t == 0)
        atomicAdd(out, 0.5f * (red[0] + red[1] + red[2] + red[3]));
}

extern "C" void kernel_launch(void* const* d_in, const int* in_sizes, int n_in,
                              void* d_out, int out_size, void* d_ws, size_t ws_size,
                              hipStream_t stream) {
    const int*   A1    = (const int*)d_in[0];
    const int*   A2    = (const int*)d_in[1];
    const int*   l1    = (const int*)d_in[2];
    const int*   l2    = (const int*)d_in[3];
    const float* nodeW = (const float*)d_in[4];
    const float* edgeW = (const float*)d_in[5];
    float* out = (float*)d_out;
    float* Sws = (float*)d_ws;   // 96*96 floats = 36,864 B of scratch

    hipLaunchKernelGGL(ged_sinkhorn, dim3(1), dim3(1024), 0, stream,
                       l1, l2, nodeW, Sws, out);
    hipLaunchKernelGGL(ged_quad, dim3(NP), dim3(256), 0, stream,
                       A1, A2, edgeW, Sws, out);
}

// Round 2
// 43.844 us; speedup vs baseline: 1.1920x; 1.1920x over previous
//
#include <hip/hip_runtime.h>

#define NP 96          // Np = Mp = 96 (95 nodes + 1 eps)
#define NREAL 95
#define NLAB 8
#define SINK_ITERS 10

// ---------------------------------------------------------------------------
// K1: single block, 1024 threads = 16 waves. Wave w owns rows 6w..6w+5.
// Lane l holds S[row][l] and S[row][64+l] (latter only for l<32) in REGISTERS
// for the entire Sinkhorn run. Per iteration:
//   - row sums: 6 interleaved 64-lane butterflies (chain depth = 6 shfl)
//   - row normalize + column partials: pure register ops
//   - column sums: one double-buffered LDS partial array, ONE barrier/iter
// Epilogue: write S to workspace, compute linear term cvec.v into out[0].
// ---------------------------------------------------------------------------
__global__ __launch_bounds__(1024) void ged_sinkhorn(
    const int* __restrict__ l1, const int* __restrict__ l2,
    const float* __restrict__ nodeW,
    float* __restrict__ S_out, float* __restrict__ out)
{
    __shared__ float NC[9][9];
    __shared__ float ENC[9][9];          // exp(-0.5*NC)
    __shared__ int   l1e[NP], l2e[NP];
    __shared__ float colp[2][16][NP];    // double-buffered per-wave column partials
    __shared__ float wpart[16];

    const int t = threadIdx.x;
    const int lane = t & 63;
    const int wave = t >> 6;
    const int r0 = wave * 6;
    const bool hasB = lane < 32;

    // Build NCx cost table + exp table
    if (t < 81) {
        int r = t / 9, c = t % 9;
        float v;
        if (r == c) v = 0.f;
        else if (r == NLAB || c == NLAB) v = fmaxf(nodeW[28], 0.f);
        else {
            int rr = min(r, c), cc = max(r, c);
            int p = rr * (15 - rr) / 2 + (cc - rr - 1);   // triu_indices(8,1)
            v = fmaxf(nodeW[p], 0.f);
        }
        NC[r][c] = v;
        ENC[r][c] = expf(-0.5f * v);
    }
    if (t < NP) {
        l1e[t] = (t < NREAL) ? l1[t] : NLAB;
        l2e[t] = (t < NREAL) ? l2[t] : NLAB;
    }
    __syncthreads();

    // Registers: a[r] = S[r0+r][lane], b[r] = S[r0+r][64+lane] (lane<32)
    const int c0 = lane, c1 = 64 + lane;
    const int lcode0 = l2e[c0];
    const int lcode1 = hasB ? l2e[c1] : 0;
    int rcode[6];
    float a[6], b[6];
    #pragma unroll
    for (int r = 0; r < 6; ++r) {
        rcode[r] = l1e[r0 + r];
        a[r] = ENC[rcode[r]][lcode0];
        b[r] = hasB ? ENC[rcode[r]][lcode1] : 0.f;
    }

    int p = 0;
    for (int iter = 0; iter < SINK_ITERS; ++iter) {
        // ---- row sums: 6 concurrent butterflies (level-outer for ILP)
        float rs[6];
        #pragma unroll
        for (int r = 0; r < 6; ++r) rs[r] = a[r] + b[r];
        #pragma unroll
        for (int off = 32; off >= 1; off >>= 1) {
            #pragma unroll
            for (int r = 0; r < 6; ++r) rs[r] += __shfl_xor(rs[r], off, 64);
        }
        // ---- row normalize + column partials (registers only)
        float cp0 = 0.f, cp1 = 0.f;
        #pragma unroll
        for (int r = 0; r < 6; ++r) {
            float inv = 1.f / rs[r];
            a[r] *= inv; b[r] *= inv;
            cp0 += a[r]; cp1 += b[r];
        }
        colp[p][wave][c0] = cp0;
        if (hasB) colp[p][wave][c1] = cp1;
        __syncthreads();
        // ---- column sums across 16 waves (broadcast-friendly reads)
        float cs0 = 0.f, cs1 = 0.f;
        #pragma unroll
        for (int q = 0; q < 16; ++q) {
            cs0 += colp[p][q][c0];
            cs1 += hasB ? colp[p][q][c1] : 0.f;
        }
        float inv0 = 1.f / cs0;
        float inv1 = hasB ? 1.f / cs1 : 0.f;
        #pragma unroll
        for (int r = 0; r < 6; ++r) { a[r] *= inv0; b[r] *= inv1; }
        p ^= 1;
        // no second barrier needed: next iter writes the other colp buffer
    }

    // ---- epilogue: write S + linear term
    float lacc = 0.f;
    #pragma unroll
    for (int r = 0; r < 6; ++r) {
        int row = r0 + r;
        S_out[row * NP + c0] = a[r];
        lacc += NC[rcode[r]][lcode0] * a[r];
        if (hasB) {
            S_out[row * NP + c1] = b[r];
            lacc += NC[rcode[r]][lcode1] * b[r];
        }
    }
    #pragma unroll
    for (int off = 32; off >= 1; off >>= 1) lacc += __shfl_xor(lacc, off, 64);
    if (lane == 0) wpart[wave] = lacc;
    __syncthreads();
    if (t == 0) {
        float tot = 0.f;
        #pragma unroll
        for (int w = 0; w < 16; ++w) tot += wpart[w];
        out[0] = tot;     // K2 atomically adds the quadratic term
    }
}

// ---------------------------------------------------------------------------
// K2: one block per k-column (96 blocks, 256 threads). Computes
//   partial_k = sum_j S[j,k] * sum_i V[i][a1c[i,j]],
//   V[i][e]   = sum_l EC[e, a2c[k,l]] * S[i,l]
// A1 codes staged in LDS as uint8 so phase B is LDS-only (pipelined).
// ---------------------------------------------------------------------------
__global__ __launch_bounds__(256) void ged_quad(
    const int* __restrict__ A1, const int* __restrict__ A2,
    const float* __restrict__ edgeW, const float* __restrict__ S_in,
    float* __restrict__ out)
{
    __shared__ float S[NP][NP + 1];       // pad: phase-A row reads conflict-free
    __shared__ unsigned char a1c[NP][NP]; // A1 codes (0..3), zero-padded
    __shared__ float EC[4][4];
    __shared__ float ecl[NP][4];          // ecl[l][e] = EC[e][a2c[k][l]]
    __shared__ float Vp[2][4][NP];        // half-range partials of V
    __shared__ float V[NP][4];            // V[i][e]
    __shared__ float red[4];

    const int k = blockIdx.x;
    const int t = threadIdx.x;

    // EC 4x4 edge cost table
    if (t < 16) {
        int r = t / 4, c = t % 4;
        float v;
        if (r == c) v = 0.f;
        else if (r == 0 || c == 0) v = fmaxf(edgeW[3], 0.f);
        else {
            int rr = min(r, c) - 1, cc = max(r, c) - 1;
            int p = rr * (5 - rr) / 2 + (cc - rr - 1);   // triu_indices(3,1)
            v = fmaxf(edgeW[p], 0.f);
        }
        EC[r][c] = v;
    }
    // Stage S (vectorized) and A1 codes
    {
        const float4* S4 = (const float4*)S_in;
        for (int e = t; e < NP * NP / 4; e += 256) {
            float4 v = S4[e];
            int r = (e * 4) / NP, c = (e * 4) % NP;
            S[r][c] = v.x; S[r][c + 1] = v.y; S[r][c + 2] = v.z; S[r][c + 3] = v.w;
        }
    }
    for (int e = t; e < NP * NP; e += 256) {
        int i = e / NP, j = e % NP;
        a1c[i][j] = (unsigned char)((i < NREAL && j < NREAL) ? A1[i * NREAL + j] : 0);
    }
    __syncthreads();

    // ecl[l][e] = EC[e][a2c[k][l]]
    if (t < NP) {
        int l = t;
        int c = (k < NREAL && l < NREAL) ? A2[k * NREAL + l] : 0;
        #pragma unroll
        for (int e = 0; e < 4; ++e) ecl[l][e] = EC[e][c];
    }
    __syncthreads();

    // Phase A: V[i][e] = sum_l ecl[l][e]*S[i][l]; 2 threads per row i
    if (t < 192) {
        int i = t >> 1, h = t & 1;
        float v0 = 0.f, v1 = 0.f, v2 = 0.f, v3 = 0.f;
        int l0 = h * 48;
        #pragma unroll 8
        for (int l = l0; l < l0 + 48; ++l) {
            float s = S[i][l];
            v0 += s * ecl[l][0];
            v1 += s * ecl[l][1];
            v2 += s * ecl[l][2];
            v3 += s * ecl[l][3];
        }
        Vp[h][0][i] = v0; Vp[h][1][i] = v1; Vp[h][2][i] = v2; Vp[h][3][i] = v3;
    }
    __syncthreads();
    if (t < NP) {
        #pragma unroll
        for (int e = 0; e < 4; ++e) V[t][e] = Vp[0][e][t] + Vp[1][e][t];
    }
    __syncthreads();

    // Phase B: pair (2 threads) per j: w = sum_i V[i][a1c[i][j]] (LDS-only)
    float part = 0.f;
    if (t < 192) {
        int j = t >> 1, h = t & 1;
        float w = 0.f;
        int i0 = h * 48;
        #pragma unroll 8
        for (int i = i0; i < i0 + 48; ++i)
            w += V[i][a1c[i][j]];
        w += __shfl_xor(w, 1, 64);       // combine the pair's halves
        if (h == 0) part = S[j][k] * w;
    }
    // Block reduce
    const int lane = t & 63, wave = t >> 6;
    #pragma unroll
    for (int off = 32; off >= 1; off >>= 1) part += __shfl_xor(part, off, 64);
    if (lane == 0) red[wave] = part;
    __syncthreads();
    if (t == 0)
        atomicAdd(out, 0.5f * (red[0] + red[1] + red[2] + red[3]));
}

extern "C" void kernel_launch(void* const* d_in, const int* in_sizes, int n_in,
                              void* d_out, int out_size, void* d_ws, size_t ws_size,
                              hipStream_t stream) {
    const int*   A1    = (const int*)d_in[0];
    const int*   A2    = (const int*)d_in[1];
    const int*   l1    = (const int*)d_in[2];
    const int*   l2    = (const int*)d_in[3];
    const float* nodeW = (const float*)d_in[4];
    const float* edgeW = (const float*)d_in[5];
    float* out = (float*)d_out;
    float* Sws = (float*)d_ws;   // 96*96 floats = 36,864 B of scratch

    hipLaunchKernelGGL(ged_sinkhorn, dim3(1), dim3(1024), 0, stream,
                       l1, l2, nodeW, Sws, out);
    hipLaunchKernelGGL(ged_quad, dim3(NP), dim3(256), 0, stream,
                       A1, A2, edgeW, Sws, out);
}

// Round 3
// 15.937 us; speedup vs baseline: 3.2794x; 2.7511x over previous
//
#include <hip/hip_runtime.h>

#define NP 96
#define NREAL 95
#define NLAB 8
#define SINK_ITERS 10

// ---------------------------------------------------------------------------
// Single fused kernel, one block of 256 threads.
//
// Key identity: M0[i,k] = W[a_i][b_k] with W = exp(-0.5*NCx), a=l1e, b=l2e.
// Sinkhorn scaling is therefore per-LABEL: S[i,k] = R[a_i]*W[a_i][b_k]*C[b_k],
// with 9-dim recurrence  R = 1/(W (cnt2.*C)),  C = 1/(W^T (cnt1.*R)).
//
// ged = 0.5 * Q2 + L, where
//   L  = sum_{a,b} cnt1[a] cnt2[b] NCx[a,b] w(a,b),      w = diag(R) W diag(C)
//   Q2 = sum_{e,f} EC[e,f] sum_{abgd} E1[e][α][β] E2[f][γ][δ] w(β,γ) w(α,δ)
//   E1[e][α][β] = #{(p,q) in 96²: a1[p,q]=e, a_p=α, a_q=β}   (4x9x9), sim. E2.
//
// Wave 0: Sinkhorn in registers. Waves 1-3: E1/E2 histograms (per-wave private
// LDS copies, int atomics). Then: pad corrections, w, L, contraction, output.
// ---------------------------------------------------------------------------
__global__ __launch_bounds__(256) void ged_fused(
    const int* __restrict__ A1, const int* __restrict__ A2,
    const int* __restrict__ l1, const int* __restrict__ l2,
    const float* __restrict__ nodeW, const float* __restrict__ edgeW,
    float* __restrict__ out)
{
    __shared__ float Wt[9][9];          // exp(-0.5*NCx)
    __shared__ float NC[9][9];          // NCx
    __shared__ float EC[4][4];
    __shared__ int   cnt1r[9], cnt2r[9];    // real-node (95) label counts
    __shared__ unsigned char lab1[NREAL], lab2[NREAL];
    __shared__ int   E1p[3][4][9][9], E2p[3][4][9][9];  // per-wave private hists
    __shared__ float E1f[4][9][9], E2f[4][9][9];
    __shared__ float RC[18];            // final R[0..8], C[0..8]
    __shared__ float wfin[9][9];
    __shared__ float P1[4][9][9], T2[4][9][9];
    __shared__ float Lred[4];

    const int t = threadIdx.x;
    const int lane = t & 63;
    const int wave = t >> 6;

    // ---- zero counters ----
    if (t < 9) { cnt1r[t] = 0; cnt2r[t] = 0; }
    for (int e = t; e < 3 * 324; e += 256) {
        ((int*)E1p)[e] = 0;
        ((int*)E2p)[e] = 0;
    }

    // ---- cost tables ----
    if (t < 81) {
        int r = t / 9, c = t % 9;
        float v;
        if (r == c) v = 0.f;
        else if (r == NLAB || c == NLAB) v = fmaxf(nodeW[28], 0.f);
        else {
            int rr = min(r, c), cc = max(r, c);
            int p = rr * (15 - rr) / 2 + (cc - rr - 1);   // triu_indices(8,1)
            v = fmaxf(nodeW[p], 0.f);
        }
        NC[r][c] = v;
        Wt[r][c] = expf(-0.5f * v);
    }
    if (t < 16) {
        int r = t / 4, c = t % 4;
        float v;
        if (r == c) v = 0.f;
        else if (r == 0 || c == 0) v = fmaxf(edgeW[3], 0.f);
        else {
            int rr = min(r, c) - 1, cc = max(r, c) - 1;
            int p = rr * (5 - rr) / 2 + (cc - rr - 1);    // triu_indices(3,1)
            v = fmaxf(edgeW[p], 0.f);
        }
        EC[r][c] = v;
    }
    __syncthreads();

    // ---- label staging + label counts ----
    if (t < NREAL) {
        int a = l1[t], b = l2[t];
        lab1[t] = (unsigned char)a;
        lab2[t] = (unsigned char)b;
        atomicAdd(&cnt1r[a], 1);
        atomicAdd(&cnt2r[b], 1);
    }
    __syncthreads();

    if (wave == 0) {
        // ================= Sinkhorn, 9-dim, in registers =================
        float w[9][9];
        #pragma unroll
        for (int a = 0; a < 9; ++a)
            #pragma unroll
            for (int b = 0; b < 9; ++b) w[a][b] = Wt[a][b];
        float c1[9], c2[9];
        #pragma unroll
        for (int a = 0; a < 9; ++a) {
            c1[a] = (float)cnt1r[a] + (a == 8 ? 1.f : 0.f);  // + eps node
            c2[a] = (float)cnt2r[a] + (a == 8 ? 1.f : 0.f);
        }
        float C[9], R[9];
        #pragma unroll
        for (int b = 0; b < 9; ++b) C[b] = 1.f;
        for (int it = 0; it < SINK_ITERS; ++it) {
            float s[9];
            #pragma unroll
            for (int b = 0; b < 9; ++b) s[b] = c2[b] * C[b];
            #pragma unroll
            for (int a = 0; a < 9; ++a) {
                float acc = 0.f;
                #pragma unroll
                for (int b = 0; b < 9; ++b) acc += w[a][b] * s[b];
                R[a] = 1.f / acc;
            }
            float r2[9];
            #pragma unroll
            for (int a = 0; a < 9; ++a) r2[a] = c1[a] * R[a];
            #pragma unroll
            for (int b = 0; b < 9; ++b) {
                float acc = 0.f;
                #pragma unroll
                for (int a = 0; a < 9; ++a) acc += w[a][b] * r2[a];
                C[b] = 1.f / acc;
            }
        }
        if (lane == 0) {
            #pragma unroll
            for (int a = 0; a < 9; ++a) { RC[a] = R[a]; RC[9 + a] = C[a]; }
        }
    } else {
        // ================= E1/E2 histograms (waves 1-3) =================
        const int hw = wave - 1;       // private copy 0..2
        const int lt = t - 64;         // 0..191
        if (lt < NREAL) {
            int p = lt;
            int alpha = lab1[p];
            const int* __restrict__ row = A1 + p * NREAL;
            for (int q = 0; q < NREAL; ++q) {
                int e = row[q];
                atomicAdd(&E1p[hw][e][alpha][lab1[q]], 1);
            }
        } else if (lt >= 96 && lt < 96 + NREAL) {
            int p = lt - 96;
            int gamma = lab2[p];
            const int* __restrict__ row = A2 + p * NREAL;
            for (int q = 0; q < NREAL; ++q) {
                int f = row[q];
                atomicAdd(&E2p[hw][f][gamma][lab2[q]], 1);
            }
        }
    }
    __syncthreads();

    // ---- combine private histograms to float ----
    for (int idx = t; idx < 324; idx += 256) {
        E1f[0][0][idx] = (float)(((int*)E1p[0])[idx] + ((int*)E1p[1])[idx] + ((int*)E1p[2])[idx]);
        E2f[0][0][idx] = (float)(((int*)E2p[0])[idx] + ((int*)E2p[1])[idx] + ((int*)E2p[2])[idx]);
    }
    __syncthreads();

    // ---- padding corrections: row 95, col 95, corner (all e=0) ----
    if (t < 9) {
        E1f[0][8][t] += (float)cnt1r[t];      // (95, q): α=8, β=lab1[q]
        E1f[0][t][8] += (float)cnt1r[t];      // (p, 95): β=8
        E2f[0][8][t] += (float)cnt2r[t];
        E2f[0][t][8] += (float)cnt2r[t];
        if (t == 8) { E1f[0][8][8] += 1.f; E2f[0][8][8] += 1.f; }  // corner
    }
    __syncthreads();

    // ---- final w(a,b) + linear term ----
    float Lpart = 0.f;
    if (t < 81) {
        int a = t / 9, b = t % 9;
        float wv = RC[a] * Wt[a][b] * RC[9 + b];
        wfin[a][b] = wv;
        float c1f = (float)cnt1r[a] + (a == 8 ? 1.f : 0.f);
        float c2f = (float)cnt2r[b] + (b == 8 ? 1.f : 0.f);
        Lpart = c1f * c2f * NC[a][b] * wv;
    }
    #pragma unroll
    for (int off = 32; off >= 1; off >>= 1) Lpart += __shfl_xor(Lpart, off, 64);
    if (lane == 0) Lred[wave] = Lpart;
    __syncthreads();   // also orders wfin before P1/T2 reads

    // ---- contractions: P1[e][β][δ] = Σ_α E1[e][α][β] w(α,δ)
    //                    T2[f][β][δ] = Σ_γ E2[f][γ][δ] w(β,γ)
    for (int idx = t; idx < 324; idx += 256) {
        int e = idx / 81, r = idx % 81;
        int beta = r / 9, delta = r % 9;
        float acc1 = 0.f, acc2 = 0.f;
        #pragma unroll
        for (int g = 0; g < 9; ++g) {
            acc1 += E1f[e][g][beta] * wfin[g][delta];
            acc2 += E2f[e][g][delta] * wfin[beta][g];
        }
        P1[e][beta][delta] = acc1;
        T2[e][beta][delta] = acc2;
    }
    __syncthreads();

    // ---- Q2 = Σ_{e,f} EC[e,f] Σ_{β,δ} P1[e][β][δ] T2[f][β][δ] ----
    float qpart = 0.f;
    if (t < 16) {
        int e = t / 4, f = t % 4;
        float acc = 0.f;
        #pragma unroll
        for (int bd = 0; bd < 81; ++bd) {
            int beta = bd / 9, delta = bd % 9;
            acc += P1[e][beta][delta] * T2[f][beta][delta];
        }
        qpart = EC[e][f] * acc;
    }
    #pragma unroll
    for (int off = 8; off >= 1; off >>= 1) qpart += __shfl_xor(qpart, off, 64);
    if (t == 0) {
        float L = Lred[0] + Lred[1] + Lred[2] + Lred[3];
        out[0] = 0.5f * qpart + L;
    }
}

extern "C" void kernel_launch(void* const* d_in, const int* in_sizes, int n_in,
                              void* d_out, int out_size, void* d_ws, size_t ws_size,
                              hipStream_t stream) {
    const int*   A1    = (const int*)d_in[0];
    const int*   A2    = (const int*)d_in[1];
    const int*   l1    = (const int*)d_in[2];
    const int*   l2    = (const int*)d_in[3];
    const float* nodeW = (const float*)d_in[4];
    const float* edgeW = (const float*)d_in[5];
    float* out = (float*)d_out;

    hipLaunchKernelGGL(ged_fused, dim3(1), dim3(256), 0, stream,
                       A1, A2, l1, l2, nodeW, edgeW, out);
}